// Round 1
// baseline (75.236 us; speedup 1.0000x reference)
//
#include <hip/hip_runtime.h>

#define NBINS 10

// Zero the 30 global accumulators (ws is poisoned 0xAA and never re-poisoned).
__global__ void uce_zero(float* __restrict__ acc) {
    int i = threadIdx.x;
    if (i < 3 * NBINS) acc[i] = 0.0f;
}

// Main pass: grid-stride float4 loads, per-thread register histograms,
// wave shuffle-reduce, LDS block accumulate, one global atomicAdd per counter.
__global__ __launch_bounds__(256) void uce_hist(const float* __restrict__ up,
                                                const float* __restrict__ ep,
                                                float* __restrict__ acc, int n4) {
    float cnt[NBINS], su[NBINS], se[NBINS];
#pragma unroll
    for (int b = 0; b < NBINS; ++b) { cnt[b] = 0.0f; su[b] = 0.0f; se[b] = 0.0f; }

    const float4* __restrict__ u4 = (const float4*)up;
    const float4* __restrict__ e4 = (const float4*)ep;
    int stride = gridDim.x * blockDim.x;
    for (int i = blockIdx.x * blockDim.x + threadIdx.x; i < n4; i += stride) {
        float4 uu = u4[i];
        float4 ee = e4[i];
        float us[4] = {uu.x, uu.y, uu.z, uu.w};
        float es[4] = {ee.x, ee.y, ee.z, ee.w};
#pragma unroll
        for (int k = 0; k < 4; ++k) {
            float u = us[k];
            float e = es[k];
            // bin i iff boundaries[i] < u <= boundaries[i+1], boundaries[i] = fl(i*0.1f)
            // (matches jnp.linspace f32: iota * fl(1/10)). Guess + 1-step fixup.
            int g = (int)(u * 10.0f);
            g = g > 9 ? 9 : g;              // u<0 truncates to <=0, handled below
            float lo = (float)g * 0.1f;
            float hi = (float)(g + 1) * 0.1f;
            if (u <= lo)      g -= 1;       // also routes u<=0 to g=-1 (invalid)
            else if (u > hi)  g += 1;
            g = (g > 9) ? -1 : g;           // u>1.0 -> invalid
#pragma unroll
            for (int b = 0; b < NBINS; ++b) {
                bool m = (g == b);
                cnt[b] += m ? 1.0f : 0.0f;
                su[b]  += m ? u : 0.0f;
                se[b]  += m ? e : 0.0f;
            }
        }
    }

    // wave (64-lane) shuffle reduction
    int lane = threadIdx.x & 63;
    __shared__ float part[3 * NBINS];
    if (threadIdx.x < 3 * NBINS) part[threadIdx.x] = 0.0f;
    __syncthreads();
#pragma unroll
    for (int b = 0; b < NBINS; ++b) {
        float c = cnt[b], s1 = su[b], s2 = se[b];
#pragma unroll
        for (int off = 32; off > 0; off >>= 1) {
            c  += __shfl_down(c, off, 64);
            s1 += __shfl_down(s1, off, 64);
            s2 += __shfl_down(s2, off, 64);
        }
        if (lane == 0) {
            atomicAdd(&part[b], c);
            atomicAdd(&part[NBINS + b], s1);
            atomicAdd(&part[2 * NBINS + b], s2);
        }
    }
    __syncthreads();
    if (threadIdx.x < 3 * NBINS) atomicAdd(&acc[threadIdx.x], part[threadIdx.x]);
}

// Finalize: UCE = sum over nonempty bins of |avg_u - avg_e| * (count/n)
__global__ void uce_final(const float* __restrict__ acc, float* __restrict__ out,
                          float inv_n) {
    if (threadIdx.x == 0 && blockIdx.x == 0) {
        float uce = 0.0f;
#pragma unroll
        for (int b = 0; b < NBINS; ++b) {
            float c = acc[b];
            if (c > 0.0f) {
                float au = acc[NBINS + b] / c;
                float ae = acc[2 * NBINS + b] / c;
                uce += fabsf(au - ae) * (c * inv_n);
            }
        }
        out[0] = uce;
    }
}

extern "C" void kernel_launch(void* const* d_in, const int* in_sizes, int n_in,
                              void* d_out, int out_size, void* d_ws, size_t ws_size,
                              hipStream_t stream) {
    const float* u = (const float*)d_in[0];
    const float* e = (const float*)d_in[1];
    float* acc = (float*)d_ws;          // 30 floats of scratch
    float* out = (float*)d_out;
    int n = in_sizes[0];
    int n4 = n >> 2;                    // N = 2^25, divisible by 4

    uce_zero<<<1, 64, 0, stream>>>(acc);
    uce_hist<<<2048, 256, 0, stream>>>(u, e, acc, n4);
    uce_final<<<1, 64, 0, stream>>>(acc, out, 1.0f / (float)n);
}